// Round 5
// baseline (250.488 us; speedup 1.0000x reference)
//
#include <hip/hip_runtime.h>
#include <hip/hip_bf16.h>

#define GAT_ALPHA 0.2f
#define LOG2E 1.4426950408889634f

typedef float f32x4 __attribute__((ext_vector_type(4)));
typedef int   i32x4 __attribute__((ext_vector_type(4)));
typedef short bf16x8 __attribute__((ext_vector_type(8)));

static constexpr int Nn  = 2048;
static constexpr int FIN = 256;
static constexpr int FO  = 128;

static __device__ __forceinline__ unsigned short f2bf(float x) {
    __hip_bfloat16 h = __float2bfloat16(x);
    return __builtin_bit_cast(unsigned short, h);
}
static __device__ __forceinline__ float bf2f(unsigned short u) {
    unsigned int v = ((unsigned int)u) << 16;
    return __builtin_bit_cast(float, v);
}

// ---------------------------------------------------------------------------
// Kernel A: compress adj (134 MB int32) -> 1 bit/edge (4.2 MB).
// Pure stream: each thread does 8 consecutive ints -> 1 byte, coalesced.
// ---------------------------------------------------------------------------
__global__ __launch_bounds__(256) void gat_adjbits(
        const int* __restrict__ adj, unsigned char* __restrict__ mbytes)
{
    const int g = blockIdx.x * 256 + threadIdx.x;
    #pragma unroll 4
    for (int it = 0; it < 16; ++it) {
        const size_t bi = (size_t)it * 262144 + (size_t)g;   // byte index
        const int* p = adj + (bi << 3);
        i32x4 v0 = *(const i32x4*)(p);
        i32x4 v1 = *(const i32x4*)(p + 4);
        unsigned int m = 0;
        m |= (v0[0] > 0) ? 1u   : 0u;
        m |= (v0[1] > 0) ? 2u   : 0u;
        m |= (v0[2] > 0) ? 4u   : 0u;
        m |= (v0[3] > 0) ? 8u   : 0u;
        m |= (v1[0] > 0) ? 16u  : 0u;
        m |= (v1[1] > 0) ? 32u  : 0u;
        m |= (v1[2] > 0) ? 64u  : 0u;
        m |= (v1[3] > 0) ? 128u : 0u;
        mbytes[bi] = (unsigned char)m;
    }
}

// ---------------------------------------------------------------------------
// Kernel 0 (prep): wa = W@a (both halves); inits md_key[8]=0 (key of -inf).
// ---------------------------------------------------------------------------
__global__ __launch_bounds__(256) void gat_prep(
        const float* __restrict__ W, const float* __restrict__ a,
        float* __restrict__ wa, unsigned int* __restrict__ md_key)
{
    __shared__ float pr[32][8];
    __shared__ float pd[32][8];
    const int t = threadIdx.x;
    const int kl = t >> 3, seg = t & 7;
    const int k = blockIdx.x * 32 + kl;
    float ps = 0.f, pv = 0.f;
    const float* wr = W + (size_t)k * FO + seg * 16;
    #pragma unroll
    for (int f = 0; f < 16; f += 4) {
        f32x4 wv = *(const f32x4*)(wr + f);
        f32x4 as = *(const f32x4*)(a + seg * 16 + f);
        f32x4 ad = *(const f32x4*)(a + FO + seg * 16 + f);
        ps += wv[0]*as[0] + wv[1]*as[1] + wv[2]*as[2] + wv[3]*as[3];
        pv += wv[0]*ad[0] + wv[1]*ad[1] + wv[2]*ad[2] + wv[3]*ad[3];
    }
    pr[kl][seg] = ps; pd[kl][seg] = pv;
    __syncthreads();
    if (t < 32) {
        float s = 0.f, d = 0.f;
        #pragma unroll
        for (int j = 0; j < 8; ++j) { s += pr[t][j]; d += pd[t][j]; }
        wa[blockIdx.x * 32 + t]       = s;
        wa[256 + blockIdx.x * 32 + t] = d;
    }
    if (blockIdx.x == 0 && t < 8) md_key[t] = 0u;
}

// ---------------------------------------------------------------------------
// Kernel 1: Wh = h@W via MFMA, stored PRE-SWIZZLED in B-fragment order:
//   WhB[b][K][nt][lane][8]  (K = j/32 kstep, nt = f/16 tile, lane=(quad',n16))
// so gat_attn's B-loads are contiguous 1 KB per wave. s_src/s_dst fp32-exact
// via wa; per-batch max(s_dst) via order-preserving uint atomicMax.
// ---------------------------------------------------------------------------
__global__ __launch_bounds__(256) void gat_wh(
        const float* __restrict__ h, const float* __restrict__ W,
        const float* __restrict__ wa, unsigned short* __restrict__ WhB,
        float* __restrict__ s_src, float* __restrict__ s_dst,
        unsigned int* __restrict__ md_key)
{
    __shared__ unsigned short WT[FO][264];  // [f][k] bf16, padded
    __shared__ float wal[512];
    __shared__ float sred[64][4][2];
    __shared__ float red64[64];
    const int t  = threadIdx.x;
    const int b  = blockIdx.x & 7;
    const int n0 = (blockIdx.x >> 3) << 6;

    if (t < 128) *(f32x4*)&wal[t * 4] = *(const f32x4*)&wa[t * 4];
    #pragma unroll
    for (int c = 0; c < 32; ++c) {
        int flat = c * 1024 + t * 4;
        int k = flat >> 7, f = flat & 127;
        f32x4 wv = *(const f32x4*)&W[flat];
        WT[f + 0][k] = f2bf(wv[0]);
        WT[f + 1][k] = f2bf(wv[1]);
        WT[f + 2][k] = f2bf(wv[2]);
        WT[f + 3][k] = f2bf(wv[3]);
    }
    __syncthreads();

    {
        const int row = t >> 2, seg = t & 3;
        const float* hp  = h + ((size_t)(b * Nn + n0 + row)) * FIN + seg * 64;
        const float* was = &wal[seg * 64];
        const float* wad = &wal[256 + seg * 64];
        float ps = 0.f, pv = 0.f;
        #pragma unroll
        for (int j = 0; j < 64; j += 4) {
            f32x4 hv = *(const f32x4*)(hp + j);
            f32x4 sv = *(const f32x4*)(was + j);
            f32x4 dv = *(const f32x4*)(wad + j);
            ps += hv[0]*sv[0] + hv[1]*sv[1] + hv[2]*sv[2] + hv[3]*sv[3];
            pv += hv[0]*dv[0] + hv[1]*dv[1] + hv[2]*dv[2] + hv[3]*dv[3];
        }
        sred[row][seg][0] = ps;
        sred[row][seg][1] = pv;
    }
    __syncthreads();
    if (t < 64) {
        float s = sred[t][0][0] + sred[t][1][0] + sred[t][2][0] + sred[t][3][0];
        float d = sred[t][0][1] + sred[t][1][1] + sred[t][2][1] + sred[t][3][1];
        s_src[b * Nn + n0 + t] = s;
        s_dst[b * Nn + n0 + t] = d;
        red64[t] = d;
    }
    __syncthreads();
    if (t < 16) red64[t] = fmaxf(fmaxf(red64[t], red64[t + 16]),
                                 fmaxf(red64[t + 32], red64[t + 48]));
    __syncthreads();
    if (t == 0) {
        float m = red64[0];
        #pragma unroll
        for (int j = 1; j < 16; ++j) m = fmaxf(m, red64[j]);
        unsigned int bits = __builtin_bit_cast(unsigned int, m);
        unsigned int key  = (bits & 0x80000000u) ? ~bits : (bits | 0x80000000u);
        atomicMax(md_key + b, key);
    }

    const int w = t >> 6, lane = t & 63, n16 = lane & 15, quad = lane >> 4;
    const float* ha = h + ((size_t)(b * Nn + n0 + w * 16 + n16)) * FIN + quad * 8;
    f32x4 acc[8] = {};
    #pragma unroll
    for (int ks = 0; ks < 8; ++ks) {
        f32x4 h0 = *(const f32x4*)(ha + ks * 32);
        f32x4 h1 = *(const f32x4*)(ha + ks * 32 + 4);
        bf16x8 af;
        af[0] = (short)f2bf(h0[0]); af[1] = (short)f2bf(h0[1]);
        af[2] = (short)f2bf(h0[2]); af[3] = (short)f2bf(h0[3]);
        af[4] = (short)f2bf(h1[0]); af[5] = (short)f2bf(h1[1]);
        af[6] = (short)f2bf(h1[2]); af[7] = (short)f2bf(h1[3]);
        #pragma unroll
        for (int nt = 0; nt < 8; ++nt) {
            bf16x8 bfr = *(const bf16x8*)&WT[nt * 16 + n16][ks * 32 + quad * 8];
            acc[nt] = __builtin_amdgcn_mfma_f32_16x16x32_bf16(af, bfr, acc[nt], 0, 0, 0);
        }
    }
    // C/D: element (nt, r) = Wh[n][f], f = nt*16+n16, n = n0 + w*16 + quad*4 + r.
    // B-frag target: K=(n)/32, lane'=(q2,n16), frag offset jl&7 + r.
    {
        const int K   = (n0 >> 5) + (w >> 1);
        const int jl  = ((w & 1) << 4) + (quad << 2);   // j offset within 32-block (r=0)
        const int q2  = jl >> 3;
        const int off = jl & 7;                          // 0 or 4
        unsigned short* wpb = WhB + (((size_t)(b * 64 + K)) << 12)
                                  + (((q2 << 4) + n16) << 3) + off;
        #pragma unroll
        for (int nt = 0; nt < 8; ++nt) {
            ushort4 pk;
            pk.x = f2bf(acc[nt][0]); pk.y = f2bf(acc[nt][1]);
            pk.z = f2bf(acc[nt][2]); pk.w = f2bf(acc[nt][3]);
            *(ushort4*)(wpb + ((size_t)nt << 9)) = pk;
        }
    }
}

// ---------------------------------------------------------------------------
// Kernel 2 (v4): barrier-free K-loop. 512 blocks = 8 batches x 64 i-tiles(32).
// Stage s_dst + 32 mask rows to LDS once; each wave owns ksteps s*4+w.
// A-frags computed in registers straight in MFMA A-layout (mask bits from
// LDS); B-frags are contiguous 1 KB loads from pre-swizzled WhB.
// ---------------------------------------------------------------------------
__global__ __launch_bounds__(256, 2) void gat_attn(
        const unsigned long long* __restrict__ mbits,
        const unsigned short* __restrict__ WhB,
        const float* __restrict__ s_src, const float* __restrict__ s_dst,
        const unsigned int* __restrict__ md_key, float* __restrict__ out)
{
    __shared__ float sdl[2048];                       // 8 KB
    __shared__ unsigned long long msk[32][34];        // 8.5 KB (pad: 2-way free)
    __shared__ float accbuf[2][32][132];              // 33.8 KB
    __shared__ float l_red[32];

    const int t = threadIdx.x, w = t >> 6, lane = t & 63;
    const int n16 = lane & 15, quad = lane >> 4;
    const int b  = blockIdx.x & 7;                    // batch per XCD
    const int i0 = (blockIdx.x >> 3) << 5;

    #pragma unroll
    for (int c = 0; c < 2; ++c) {
        int idx = (c << 10) + (t << 2);
        *(f32x4*)&sdl[idx] = *(const f32x4*)&s_dst[b * Nn + idx];
    }
    {
        int row = t >> 3, cc = t & 7;
        const unsigned long long* mr = mbits + ((size_t)(b * Nn + i0 + row) << 5) + (cc << 2);
        ulonglong2 m0 = *(const ulonglong2*)(mr);
        ulonglong2 m1 = *(const ulonglong2*)(mr + 2);
        msk[row][(cc << 2) + 0] = m0.x; msk[row][(cc << 2) + 1] = m0.y;
        msk[row][(cc << 2) + 2] = m1.x; msk[row][(cc << 2) + 3] = m1.y;
    }
    if (t < 32) l_red[t] = 0.f;
    __syncthreads();

    const unsigned int key = md_key[b];
    const unsigned int mb_ = (key & 0x80000000u) ? (key ^ 0x80000000u) : ~key;
    const float mdb = __builtin_bit_cast(float, mb_);
    float ssL[2], mi[2];
    #pragma unroll
    for (int ig = 0; ig < 2; ++ig) {
        float ss = s_src[b * Nn + i0 + (ig << 4) + n16];
        float tm = ss + mdb;
        mi[ig]  = fmaxf(tm, GAT_ALPHA * tm) * LOG2E;  // row upper bound (lrelu monotone)
        ssL[ig] = ss * LOG2E;
    }

    const unsigned short* wb = WhB + ((size_t)b << 18) + ((size_t)lane << 3);
    f32x4 acc[2][8] = {};
    float ls0 = 0.f, ls1 = 0.f;

    for (int s = 0; s < 16; ++s) {
        const int ks = (s << 2) | w;                  // wave k-split, disjoint
        const int kw = ks << 5;
        const unsigned short* wp = wb + ((size_t)ks << 12);
        bf16x8 bfr[8];
        #pragma unroll
        for (int nt = 0; nt < 8; ++nt)
            bfr[nt] = *(const bf16x8*)(wp + (nt << 9));    // contiguous 1 KB/wave
        f32x4 d0 = *(const f32x4*)&sdl[kw + (quad << 3)];
        f32x4 d1 = *(const f32x4*)&sdl[kw + (quad << 3) + 4];
        float dv[8] = {d0[0],d0[1],d0[2],d0[3],d1[0],d1[1],d1[2],d1[3]};
        #pragma unroll
        for (int ig = 0; ig < 2; ++ig) {
            unsigned long long m64 = msk[(ig << 4) + n16][kw >> 6];
            unsigned int mh = (kw & 32) ? (unsigned int)(m64 >> 32) : (unsigned int)m64;
            mh >>= (quad << 3);
            bf16x8 af;
            float lsl = 0.f;
            #pragma unroll
            for (int jj = 0; jj < 8; ++jj) {
                float u  = __builtin_fmaf(dv[jj], LOG2E, ssL[ig]);
                float lr = fmaxf(u, GAT_ALPHA * u);
                float e  = __builtin_amdgcn_exp2f(lr - mi[ig]);
                e = ((mh >> jj) & 1u) ? e : 0.f;      // mask == exp(NEG_INF-m)->0
                unsigned short ub = f2bf(e);
                af[jj] = (short)ub;
                lsl += bf2f(ub);                      // denom consistent w/ numerator
            }
            if (ig == 0) ls0 += lsl; else ls1 += lsl;
            #pragma unroll
            for (int nt = 0; nt < 8; ++nt)
                acc[ig][nt] = __builtin_amdgcn_mfma_f32_16x16x32_bf16(af, bfr[nt], acc[ig][nt], 0, 0, 0);
        }
    }

    atomicAdd(&l_red[n16], ls0);
    atomicAdd(&l_red[16 + n16], ls1);
    if (w < 2) {
        #pragma unroll
        for (int ig = 0; ig < 2; ++ig)
            #pragma unroll
            for (int nt = 0; nt < 8; ++nt)
                #pragma unroll
                for (int rr = 0; rr < 4; ++rr)
                    accbuf[w][(ig << 4) + (quad << 2) + rr][(nt << 4) + n16] = acc[ig][nt][rr];
    }
    __syncthreads();
    if (w >= 2) {
        #pragma unroll
        for (int ig = 0; ig < 2; ++ig)
            #pragma unroll
            for (int nt = 0; nt < 8; ++nt)
                #pragma unroll
                for (int rr = 0; rr < 4; ++rr)
                    accbuf[w - 2][(ig << 4) + (quad << 2) + rr][(nt << 4) + n16] += acc[ig][nt][rr];
    }
    __syncthreads();
    float* ob = out + ((size_t)(b * Nn + i0)) * FO;
    #pragma unroll
    for (int c = 0; c < 4; ++c) {
        int flat = (c << 10) + (t << 2);
        int m = flat >> 7, f = flat & 127;
        f32x4 v0 = *(const f32x4*)&accbuf[0][m][f];
        f32x4 v1 = *(const f32x4*)&accbuf[1][m][f];
        float l = l_red[m];
        f32x4 o;
        #pragma unroll
        for (int j = 0; j < 4; ++j) {
            float x = (v0[j] + v1[j]) / l;
            o[j] = x > 0.f ? x : expm1f(x);
        }
        *(f32x4*)&ob[(size_t)m * FO + f] = o;
    }
}

extern "C" void kernel_launch(void* const* d_in, const int* in_sizes, int n_in,
                              void* d_out, int out_size, void* d_ws, size_t ws_size,
                              hipStream_t stream)
{
    const float* h   = (const float*)d_in[0];
    const int*   adj = (const int*)d_in[1];
    const float* W   = (const float*)d_in[2];
    const float* a   = (const float*)d_in[3];
    float* out = (float*)d_out;

    // ws layout (FIXED round-4 overlap bug: s_src/s_dst are 64 KiB EACH,
    // previous layout spaced them 8 KiB apart -> s_dst clobbered s_src[b>=1]
    // and wa, corrupting scores for 7 of 8 batches):
    char* ws = (char*)d_ws;
    unsigned short* WhB   = (unsigned short*)ws;                  // [0, 4 MiB)
    unsigned char*  mbyte = (unsigned char*)(ws + 4194304);       // [4 MiB, 8 MiB)
    float* s_src          = (float*)(ws + 8388608);               // 64 KiB (8*2048*4)
    float* s_dst          = (float*)(ws + 8454144);               // 64 KiB
    float* wa             = (float*)(ws + 8519680);               // 2 KiB
    unsigned int* md_key  = (unsigned int*)(ws + 8521728);        // 32 B

    hipLaunchKernelGGL(gat_adjbits, dim3(1024), dim3(256), 0, stream, adj, mbyte);
    hipLaunchKernelGGL(gat_prep,    dim3(8),    dim3(256), 0, stream, W, a, wa, md_key);
    hipLaunchKernelGGL(gat_wh,      dim3(256),  dim3(256), 0, stream, h, W, wa, WhB, s_src, s_dst, md_key);
    hipLaunchKernelGGL(gat_attn,    dim3(512),  dim3(256), 0, stream,
                       (const unsigned long long*)mbyte, WhB, s_src, s_dst, md_key, out);
}

// Round 6
// 243.184 us; speedup vs baseline: 1.0300x; 1.0300x over previous
//
#include <hip/hip_runtime.h>
#include <hip/hip_bf16.h>

#define GAT_ALPHA 0.2f
#define LOG2E 1.4426950408889634f

typedef float f32x4 __attribute__((ext_vector_type(4)));
typedef int   i32x4 __attribute__((ext_vector_type(4)));
typedef short bf16x8 __attribute__((ext_vector_type(8)));

static constexpr int Nn  = 2048;
static constexpr int FIN = 256;
static constexpr int FO  = 128;

static __device__ __forceinline__ unsigned short f2bf(float x) {
    __hip_bfloat16 h = __float2bfloat16(x);
    return __builtin_bit_cast(unsigned short, h);
}
static __device__ __forceinline__ float bf2f(unsigned short u) {
    unsigned int v = ((unsigned int)u) << 16;
    return __builtin_bit_cast(float, v);
}

// ---------------------------------------------------------------------------
// Kernel 0 (prep): wa = W@a (both halves); inits md_key[8]=0 (key of -inf).
// ---------------------------------------------------------------------------
__global__ __launch_bounds__(256) void gat_prep(
        const float* __restrict__ W, const float* __restrict__ a,
        float* __restrict__ wa, unsigned int* __restrict__ md_key)
{
    __shared__ float pr[32][8];
    __shared__ float pd[32][8];
    const int t = threadIdx.x;
    const int kl = t >> 3, seg = t & 7;
    const int k = blockIdx.x * 32 + kl;
    float ps = 0.f, pv = 0.f;
    const float* wr = W + (size_t)k * FO + seg * 16;
    #pragma unroll
    for (int f = 0; f < 16; f += 4) {
        f32x4 wv = *(const f32x4*)(wr + f);
        f32x4 as = *(const f32x4*)(a + seg * 16 + f);
        f32x4 ad = *(const f32x4*)(a + FO + seg * 16 + f);
        ps += wv[0]*as[0] + wv[1]*as[1] + wv[2]*as[2] + wv[3]*as[3];
        pv += wv[0]*ad[0] + wv[1]*ad[1] + wv[2]*ad[2] + wv[3]*ad[3];
    }
    pr[kl][seg] = ps; pd[kl][seg] = pv;
    __syncthreads();
    if (t < 32) {
        float s = 0.f, d = 0.f;
        #pragma unroll
        for (int j = 0; j < 8; ++j) { s += pr[t][j]; d += pd[t][j]; }
        wa[blockIdx.x * 32 + t]       = s;
        wa[256 + blockIdx.x * 32 + t] = d;
    }
    if (blockIdx.x == 0 && t < 8) md_key[t] = 0u;
}

// ---------------------------------------------------------------------------
// Kernel 1: Wh = h@W via MFMA, stored PRE-SWIZZLED in B-fragment order:
//   WhB[b][K][nt][lane][8]  (K = j/32 kstep, nt = f/16 tile, lane=(quad',n16))
// so gat_attn's B-loads are contiguous 1 KB per wave. s_src/s_dst fp32-exact
// via wa; per-batch max(s_dst) via order-preserving uint atomicMax.
// ---------------------------------------------------------------------------
__global__ __launch_bounds__(256) void gat_wh(
        const float* __restrict__ h, const float* __restrict__ W,
        const float* __restrict__ wa, unsigned short* __restrict__ WhB,
        float* __restrict__ s_src, float* __restrict__ s_dst,
        unsigned int* __restrict__ md_key)
{
    __shared__ unsigned short WT[FO][264];  // [f][k] bf16, padded
    __shared__ float wal[512];
    __shared__ float sred[64][4][2];
    __shared__ float red64[64];
    const int t  = threadIdx.x;
    const int b  = blockIdx.x & 7;
    const int n0 = (blockIdx.x >> 3) << 6;

    if (t < 128) *(f32x4*)&wal[t * 4] = *(const f32x4*)&wa[t * 4];
    #pragma unroll
    for (int c = 0; c < 32; ++c) {
        int flat = c * 1024 + t * 4;
        int k = flat >> 7, f = flat & 127;
        f32x4 wv = *(const f32x4*)&W[flat];
        WT[f + 0][k] = f2bf(wv[0]);
        WT[f + 1][k] = f2bf(wv[1]);
        WT[f + 2][k] = f2bf(wv[2]);
        WT[f + 3][k] = f2bf(wv[3]);
    }
    __syncthreads();

    {
        const int row = t >> 2, seg = t & 3;
        const float* hp  = h + ((size_t)(b * Nn + n0 + row)) * FIN + seg * 64;
        const float* was = &wal[seg * 64];
        const float* wad = &wal[256 + seg * 64];
        float ps = 0.f, pv = 0.f;
        #pragma unroll
        for (int j = 0; j < 64; j += 4) {
            f32x4 hv = *(const f32x4*)(hp + j);
            f32x4 sv = *(const f32x4*)(was + j);
            f32x4 dv = *(const f32x4*)(wad + j);
            ps += hv[0]*sv[0] + hv[1]*sv[1] + hv[2]*sv[2] + hv[3]*sv[3];
            pv += hv[0]*dv[0] + hv[1]*dv[1] + hv[2]*dv[2] + hv[3]*dv[3];
        }
        sred[row][seg][0] = ps;
        sred[row][seg][1] = pv;
    }
    __syncthreads();
    if (t < 64) {
        float s = sred[t][0][0] + sred[t][1][0] + sred[t][2][0] + sred[t][3][0];
        float d = sred[t][0][1] + sred[t][1][1] + sred[t][2][1] + sred[t][3][1];
        s_src[b * Nn + n0 + t] = s;
        s_dst[b * Nn + n0 + t] = d;
        red64[t] = d;
    }
    __syncthreads();
    if (t < 16) red64[t] = fmaxf(fmaxf(red64[t], red64[t + 16]),
                                 fmaxf(red64[t + 32], red64[t + 48]));
    __syncthreads();
    if (t == 0) {
        float m = red64[0];
        #pragma unroll
        for (int j = 1; j < 16; ++j) m = fmaxf(m, red64[j]);
        unsigned int bits = __builtin_bit_cast(unsigned int, m);
        unsigned int key  = (bits & 0x80000000u) ? ~bits : (bits | 0x80000000u);
        atomicMax(md_key + b, key);
    }

    const int w = t >> 6, lane = t & 63, n16 = lane & 15, quad = lane >> 4;
    const float* ha = h + ((size_t)(b * Nn + n0 + w * 16 + n16)) * FIN + quad * 8;
    f32x4 acc[8] = {};
    #pragma unroll
    for (int ks = 0; ks < 8; ++ks) {
        f32x4 h0 = *(const f32x4*)(ha + ks * 32);
        f32x4 h1 = *(const f32x4*)(ha + ks * 32 + 4);
        bf16x8 af;
        af[0] = (short)f2bf(h0[0]); af[1] = (short)f2bf(h0[1]);
        af[2] = (short)f2bf(h0[2]); af[3] = (short)f2bf(h0[3]);
        af[4] = (short)f2bf(h1[0]); af[5] = (short)f2bf(h1[1]);
        af[6] = (short)f2bf(h1[2]); af[7] = (short)f2bf(h1[3]);
        #pragma unroll
        for (int nt = 0; nt < 8; ++nt) {
            bf16x8 bfr = *(const bf16x8*)&WT[nt * 16 + n16][ks * 32 + quad * 8];
            acc[nt] = __builtin_amdgcn_mfma_f32_16x16x32_bf16(af, bfr, acc[nt], 0, 0, 0);
        }
    }
    // C/D: element (nt, r) = Wh[n][f], f = nt*16+n16, n = n0 + w*16 + quad*4 + r.
    // B-frag target: K=(n)/32, lane'=(q2,n16), frag offset jl&7 + r.
    {
        const int K   = (n0 >> 5) + (w >> 1);
        const int jl  = ((w & 1) << 4) + (quad << 2);   // j offset within 32-block (r=0)
        const int q2  = jl >> 3;
        const int off = jl & 7;                          // 0 or 4
        unsigned short* wpb = WhB + (((size_t)(b * 64 + K)) << 12)
                                  + (((q2 << 4) + n16) << 3) + off;
        #pragma unroll
        for (int nt = 0; nt < 8; ++nt) {
            ushort4 pk;
            pk.x = f2bf(acc[nt][0]); pk.y = f2bf(acc[nt][1]);
            pk.z = f2bf(acc[nt][2]); pk.w = f2bf(acc[nt][3]);
            *(ushort4*)(wpb + ((size_t)nt << 9)) = pk;
        }
    }
}

// ---------------------------------------------------------------------------
// Kernel 2 (v5): adj stream FUSED into the prologue (no separate adjbits
// kernel, no 4.2 MB mask round-trip). Each block reads its own 32 adj rows
// (256 KB, disjoint partition, fully coalesced: thread t reads 32 consecutive
// ints = 128 B per sweep) and packs 1 bit/edge into LDS. Then the proven v4
// barrier-free K-loop: A-frags computed in registers in MFMA A-layout (mask
// bits from LDS), B-frags contiguous 1 KB wave loads from pre-swizzled WhB.
// ---------------------------------------------------------------------------
__global__ __launch_bounds__(256, 3) void gat_attn(
        const int* __restrict__ adj,
        const unsigned short* __restrict__ WhB,
        const float* __restrict__ s_src, const float* __restrict__ s_dst,
        const unsigned int* __restrict__ md_key, float* __restrict__ out)
{
    __shared__ float sdl[2048];                       // 8 KB
    __shared__ unsigned long long msk[32][34];        // 8.5 KB (row stride 68 u32)
    __shared__ float accbuf[2][32][132];              // 33.8 KB
    __shared__ float l_red[32];

    const int t = threadIdx.x, w = t >> 6, lane = t & 63;
    const int n16 = lane & 15, quad = lane >> 4;
    const int b  = blockIdx.x & 7;                    // batch per XCD
    const int i0 = (blockIdx.x >> 3) << 5;

    // ---- fused adj -> bitmask prologue ----
    // Block region: ints [(b*Nn + i0)*Nn, +65536). Sweep s: thread t packs
    // word w_i = s*256+t covering ints [w_i*32, +32) -> LDS u32 at
    // row (w_i>>6), col (w_i&63). Wave writes one row, cols=lane: 2-way free.
    {
        const int* ab = adj + ((size_t)(b * Nn + i0)) * Nn;
        unsigned int* mskw = (unsigned int*)&msk[0][0];
        #pragma unroll 2
        for (int s = 0; s < 8; ++s) {
            const int* p = ab + (s << 13) + (t << 5);
            unsigned int m = 0;
            #pragma unroll
            for (int c = 0; c < 8; ++c) {
                i32x4 v = *(const i32x4*)(p + (c << 2));
                m |= (v[0] > 0 ? 1u : 0u) << (c * 4 + 0);
                m |= (v[1] > 0 ? 1u : 0u) << (c * 4 + 1);
                m |= (v[2] > 0 ? 1u : 0u) << (c * 4 + 2);
                m |= (v[3] > 0 ? 1u : 0u) << (c * 4 + 3);
            }
            const int wi = (s << 8) + t;
            mskw[(wi >> 6) * 68 + (wi & 63)] = m;
        }
    }
    #pragma unroll
    for (int c = 0; c < 2; ++c) {
        int idx = (c << 10) + (t << 2);
        *(f32x4*)&sdl[idx] = *(const f32x4*)&s_dst[b * Nn + idx];
    }
    if (t < 32) l_red[t] = 0.f;
    __syncthreads();

    const unsigned int key = md_key[b];
    const unsigned int mb_ = (key & 0x80000000u) ? (key ^ 0x80000000u) : ~key;
    const float mdb = __builtin_bit_cast(float, mb_);
    float ssL[2], mi[2];
    #pragma unroll
    for (int ig = 0; ig < 2; ++ig) {
        float ss = s_src[b * Nn + i0 + (ig << 4) + n16];
        float tm = ss + mdb;
        mi[ig]  = fmaxf(tm, GAT_ALPHA * tm) * LOG2E;  // row upper bound (lrelu monotone)
        ssL[ig] = ss * LOG2E;
    }

    const unsigned short* wb = WhB + ((size_t)b << 18) + ((size_t)lane << 3);
    f32x4 acc[2][8] = {};
    float ls0 = 0.f, ls1 = 0.f;

    for (int s = 0; s < 16; ++s) {
        const int ks = (s << 2) | w;                  // wave k-split, disjoint
        const int kw = ks << 5;
        const unsigned short* wp = wb + ((size_t)ks << 12);
        bf16x8 bfr[8];
        #pragma unroll
        for (int nt = 0; nt < 8; ++nt)
            bfr[nt] = *(const bf16x8*)(wp + (nt << 9));    // contiguous 1 KB/wave
        f32x4 d0 = *(const f32x4*)&sdl[kw + (quad << 3)];
        f32x4 d1 = *(const f32x4*)&sdl[kw + (quad << 3) + 4];
        float dv[8] = {d0[0],d0[1],d0[2],d0[3],d1[0],d1[1],d1[2],d1[3]};
        #pragma unroll
        for (int ig = 0; ig < 2; ++ig) {
            unsigned long long m64 = msk[(ig << 4) + n16][kw >> 6];
            unsigned int mh = (kw & 32) ? (unsigned int)(m64 >> 32) : (unsigned int)m64;
            mh >>= (quad << 3);
            bf16x8 af;
            float lsl = 0.f;
            #pragma unroll
            for (int jj = 0; jj < 8; ++jj) {
                float u  = __builtin_fmaf(dv[jj], LOG2E, ssL[ig]);
                float lr = fmaxf(u, GAT_ALPHA * u);
                float e  = __builtin_amdgcn_exp2f(lr - mi[ig]);
                e = ((mh >> jj) & 1u) ? e : 0.f;      // mask == exp(NEG_INF-m)->0
                unsigned short ub = f2bf(e);
                af[jj] = (short)ub;
                lsl += bf2f(ub);                      // denom consistent w/ numerator
            }
            if (ig == 0) ls0 += lsl; else ls1 += lsl;
            #pragma unroll
            for (int nt = 0; nt < 8; ++nt)
                acc[ig][nt] = __builtin_amdgcn_mfma_f32_16x16x32_bf16(af, bfr[nt], acc[ig][nt], 0, 0, 0);
        }
    }

    atomicAdd(&l_red[n16], ls0);
    atomicAdd(&l_red[16 + n16], ls1);
    if (w < 2) {
        #pragma unroll
        for (int ig = 0; ig < 2; ++ig)
            #pragma unroll
            for (int nt = 0; nt < 8; ++nt)
                #pragma unroll
                for (int rr = 0; rr < 4; ++rr)
                    accbuf[w][(ig << 4) + (quad << 2) + rr][(nt << 4) + n16] = acc[ig][nt][rr];
    }
    __syncthreads();
    if (w >= 2) {
        #pragma unroll
        for (int ig = 0; ig < 2; ++ig)
            #pragma unroll
            for (int nt = 0; nt < 8; ++nt)
                #pragma unroll
                for (int rr = 0; rr < 4; ++rr)
                    accbuf[w - 2][(ig << 4) + (quad << 2) + rr][(nt << 4) + n16] += acc[ig][nt][rr];
    }
    __syncthreads();
    float* ob = out + ((size_t)(b * Nn + i0)) * FO;
    #pragma unroll
    for (int c = 0; c < 4; ++c) {
        int flat = (c << 10) + (t << 2);
        int m = flat >> 7, f = flat & 127;
        f32x4 v0 = *(const f32x4*)&accbuf[0][m][f];
        f32x4 v1 = *(const f32x4*)&accbuf[1][m][f];
        float l = l_red[m];
        f32x4 o;
        #pragma unroll
        for (int j = 0; j < 4; ++j) {
            float x = (v0[j] + v1[j]) / l;
            o[j] = x > 0.f ? x : expm1f(x);
        }
        *(f32x4*)&ob[(size_t)m * FO + f] = o;
    }
}

extern "C" void kernel_launch(void* const* d_in, const int* in_sizes, int n_in,
                              void* d_out, int out_size, void* d_ws, size_t ws_size,
                              hipStream_t stream)
{
    const float* h   = (const float*)d_in[0];
    const int*   adj = (const int*)d_in[1];
    const float* W   = (const float*)d_in[2];
    const float* a   = (const float*)d_in[3];
    float* out = (float*)d_out;

    // ws layout (non-overlapping; s_src/s_dst are 64 KiB EACH):
    char* ws = (char*)d_ws;
    unsigned short* WhB   = (unsigned short*)ws;                  // [0, 4 MiB)
    float* s_src          = (float*)(ws + 8388608);               // 64 KiB (8*2048*4)
    float* s_dst          = (float*)(ws + 8454144);               // 64 KiB
    float* wa             = (float*)(ws + 8519680);               // 2 KiB
    unsigned int* md_key  = (unsigned int*)(ws + 8521728);        // 32 B

    hipLaunchKernelGGL(gat_prep, dim3(8),   dim3(256), 0, stream, W, a, wa, md_key);
    hipLaunchKernelGGL(gat_wh,   dim3(256), dim3(256), 0, stream, h, W, wa, WhB, s_src, s_dst, md_key);
    hipLaunchKernelGGL(gat_attn, dim3(512), dim3(256), 0, stream, adj, WhB, s_src, s_dst, md_key, out);
}